// Round 6
// baseline (8767.685 us; speedup 1.0000x reference)
//
#include <hip/hip_runtime.h>
#include <stdint.h>

// mLSTM T=512,B=256,I=H=512 — fp32-equivalent via fp16 hi/lo MFMA (3-pass).
// Round 6: round-4 structure (proven correct, agent-scope everywhere) +
//  (1) slot-based group barrier (no atomic RMW contention),
//  (2) 16B sc1 state loads from separate hi/lo planes, single vmcnt(0) wait.
// ws layout (bytes):
//   xh     @ 0          x hi fp16                 134,217,728
//   xl     @ 134217728  x lo fp16 (scaled 2^11)   134,217,728
//   wpre_h @ 268435456  [W_ih;mx_w] frags hi        2,621,440
//   wpre_l @ 271056896  lo                          2,621,440
//   wrec_h @ 273678336  [W_hh;mh_w] frags hi        2,621,440
//   wrec_l @ 276299776  lo                          2,621,440
//   blob   @ 278921216  xg/xm fp32, 1 chunk (128 steps) 335,544,320
//   hh     @ 614465536  h hi plane u16[256][512]     262,144
//   hl     @ 614727680  h lo plane                   262,144
//   mhp    @ 614989824  m hi plane                   262,144
//   mlp    @ 615251968  m lo plane                   262,144
//   cbuf   @ 615514112  c state fp32                 524,288
//   flags  @ 616038400  8 groups x 64 u32 slots        2,048
// total 616,040,448

typedef __attribute__((ext_vector_type(8))) short s8v;
typedef __attribute__((ext_vector_type(8))) _Float16 h8v;
typedef __attribute__((ext_vector_type(4))) float f4v;

#define SC 2048.0f
#define ISC (1.0f / 2048.0f)

__device__ __forceinline__ f4v mf(s8v a, s8v b, f4v c) {
  return __builtin_amdgcn_mfma_f32_16x16x32_f16(
      __builtin_bit_cast(h8v, a), __builtin_bit_cast(h8v, b), c, 0, 0, 0);
}
__device__ __forceinline__ uint16_t f2h(float x) {
  _Float16 h = (_Float16)x;
  return __builtin_bit_cast(uint16_t, h);
}
__device__ __forceinline__ void split2(float v, uint16_t& hi, uint16_t& lo) {
  _Float16 h = (_Float16)v;
  float r = v - (float)h;
  hi = __builtin_bit_cast(uint16_t, h);
  lo = f2h(r * SC);
}
__device__ __forceinline__ float sigm(float x) { return 1.0f / (1.0f + __expf(-x)); }
__device__ __forceinline__ float tanh_f(float x) { return 1.0f - 2.0f / (__expf(2.0f * x) + 1.0f); }

// ---- sc1 (device-coherent, LLC) accessors for cross-WG state ----
__device__ __forceinline__ s8v ldx4_sc1(const uint16_t* p) {
  s8v r;
  asm volatile("global_load_dwordx4 %0, %1, off sc1" : "=v"(r) : "v"(p));
  return r;
}
__device__ __forceinline__ uint32_t ld32_sc1(const uint32_t* p) {
  uint32_t r;
  asm volatile("global_load_dword %0, %1, off sc1" : "=v"(r) : "v"(p));
  return r;
}
__device__ __forceinline__ void st16_sc1(uint16_t* p, uint32_t v) {
  asm volatile("global_store_short %0, %1, off sc1" ::"v"(p), "v"(v) : "memory");
}
__device__ __forceinline__ void st32_sc1(uint32_t* p, uint32_t v) {
  asm volatile("global_store_dword %0, %1, off sc1" ::"v"(p), "v"(v) : "memory");
}

// ---------------- split x fp32 -> fp16 hi/lo planes ----------------
__global__ __launch_bounds__(256) void k_split(const float* __restrict__ x,
                                               uint16_t* __restrict__ xh,
                                               uint16_t* __restrict__ xl, long n) {
  long i = ((long)blockIdx.x * 256 + threadIdx.x) * 8;
  if (i >= n) return;
  float4 a = *(const float4*)(x + i);
  float4 b = *(const float4*)(x + i + 4);
  union { uint16_t u[8]; s8v v; } oh, ol;
  float vv[8] = {a.x, a.y, a.z, a.w, b.x, b.y, b.z, b.w};
#pragma unroll
  for (int k = 0; k < 8; ++k) split2(vv[k], oh.u[k], ol.u[k]);
  *(s8v*)(xh + i) = oh.v;
  *(s8v*)(xl + i) = ol.v;
}

// ---------------- pack weights into MFMA B-fragment order, hi/lo ----------------
__global__ __launch_bounds__(64) void k_packw(const float* __restrict__ Wg,
                                              const float* __restrict__ Wm,
                                              uint16_t* __restrict__ wh,
                                              uint16_t* __restrict__ wl) {
  int s = blockIdx.x >> 4, kt = blockIdx.x & 15, l = threadIdx.x;
  const float* src = (s < 128) ? (Wg + (size_t)(s * 16 + (l & 15)) * 512)
                               : (Wm + (size_t)((s - 128) * 16 + (l & 15)) * 512);
  int k0 = kt * 32 + (l >> 4) * 8;
  float4 a = *(const float4*)(src + k0);
  float4 b = *(const float4*)(src + k0 + 4);
  union { uint16_t u[8]; s8v v; } oh, ol;
  float vv[8] = {a.x, a.y, a.z, a.w, b.x, b.y, b.z, b.w};
#pragma unroll
  for (int k = 0; k < 8; ++k) split2(vv[k], oh.u[k], ol.u[k]);
  size_t adr = ((size_t)(s * 16 + kt) * 64 + l) * 8;
  *(s8v*)(wh + adr) = oh.v;
  *(s8v*)(wl + adr) = ol.v;
}

// ---------------- one K-pass of the precompute GEMM ----------------
__device__ __forceinline__ void gpass(const uint16_t* __restrict__ Ap,
                                      const uint16_t* __restrict__ Bp,
                                      s8v* Asm, s8v* Bsm, int rowbase, int s0,
                                      f4v (&acc)[4][4]) {
  int tid = threadIdx.x;
  int wv = tid >> 6, l = tid & 63, wm = wv >> 1, wn = wv & 1;
  int arow = tid >> 1, ahalf = tid & 1, swz = (arow & 7) << 4;
  for (int ks = 0; ks < 8; ++ks) {
    __syncthreads();
    const uint16_t* asrc = Ap + (size_t)(rowbase + arow) * 512 + ks * 64;
#pragma unroll
    for (int q = 0; q < 4; ++q) {
      int pb = ahalf * 64 + q * 16;
      Asm[arow * 8 + (pb >> 4)] = *(const s8v*)(asrc + ((pb ^ swz) >> 1));
    }
#pragma unroll
    for (int q = 0; q < 4; ++q) {
      int ofs = tid * 64 + q * 16;
      int si = ofs >> 11, kti = (ofs >> 10) & 1, inner = ofs & 1023;
      Bsm[ofs >> 4] =
          *(const s8v*)(Bp + (size_t)((s0 + si) * 16 + ks * 2 + kti) * 512 + (inner >> 1));
    }
    __syncthreads();
#pragma unroll
    for (int kti = 0; kti < 2; ++kti) {
      s8v a[4], b[4];
#pragma unroll
      for (int i = 0; i < 4; ++i) {
        int row = wm * 64 + i * 16 + (l & 15);
        int lb = kti * 64 + (l >> 4) * 16;
        a[i] = Asm[row * 8 + ((lb ^ ((l & 7) << 4)) >> 4)];
      }
#pragma unroll
      for (int jj = 0; jj < 4; ++jj) b[jj] = Bsm[((wn * 4 + jj) * 2 + kti) * 64 + l];
#pragma unroll
      for (int i = 0; i < 4; ++i)
#pragma unroll
        for (int jj = 0; jj < 4; ++jj) acc[i][jj] = mf(a[i], b[jj], acc[i][jj]);
    }
  }
}

// ---------------- 3-pass precompute GEMM, fp32 blob out ----------------
__global__ __launch_bounds__(256, 2) void k_gemm3(const uint16_t* __restrict__ xh,
                                                  const uint16_t* __restrict__ xl,
                                                  const uint16_t* __restrict__ wh,
                                                  const uint16_t* __restrict__ wl,
                                                  float* __restrict__ blob, int row0) {
  __shared__ s8v Asm[1024], Bsm[1024];
  f4v acc_a[4][4], acc_c[4][4];
#pragma unroll
  for (int i = 0; i < 4; ++i)
#pragma unroll
    for (int jj = 0; jj < 4; ++jj) {
      acc_a[i][jj] = (f4v){0.f, 0.f, 0.f, 0.f};
      acc_c[i][jj] = (f4v){0.f, 0.f, 0.f, 0.f};
    }
  int s0 = blockIdx.x * 8, r0 = blockIdx.y * 128;
  int rowbase = row0 + r0;
  gpass(xh, wh, Asm, Bsm, rowbase, s0, acc_a);
  gpass(xh, wl, Asm, Bsm, rowbase, s0, acc_c);
  gpass(xl, wh, Asm, Bsm, rowbase, s0, acc_c);
  int tid = threadIdx.x, wv = tid >> 6, l = tid & 63, wm = wv >> 1, wn = wv & 1;
#pragma unroll
  for (int i = 0; i < 4; ++i)
#pragma unroll
    for (int jj = 0; jj < 4; ++jj) {
      int s = s0 + wn * 4 + jj;
#pragma unroll
      for (int ri = 0; ri < 4; ++ri) {
        int trow = r0 + wm * 64 + i * 16 + (l >> 4) * 4 + ri;
        int tt = trow >> 8, gg = (trow >> 5) & 7, rr = trow & 31;
        size_t adr = ((size_t)(tt * 160 + s) * 8 + gg) * 512 + rr * 16 + (l & 15);
        blob[adr] = acc_a[i][jj][ri] + acc_c[i][jj][ri] * ISC;
      }
    }
}

// ---------------- slot-based group barrier (32 WGs per batch-group) ----------------
// Arrival: one sc1 store of the epoch into this WG's slot (no RMW contention).
// Poll: wave 0's lanes each watch one slot; pass when all >= ep (monotone).
// Ordering: per-wave vmcnt(0) drains all state stores before __syncthreads;
// leader's arrival store is issued after, so observers see state before epoch.
__device__ __forceinline__ void gbar(uint32_t* slots, int myslot, uint32_t ep) {
  asm volatile("s_waitcnt vmcnt(0)" ::: "memory");
  __syncthreads();
  int tid = threadIdx.x;
  if (tid == 0) st32_sc1(slots + myslot, ep);
  if (tid < 64) {
    uint32_t v;
    const uint32_t* q = slots + (tid & 31);
    do {
      __builtin_amdgcn_s_sleep(1);
      v = ld32_sc1(q);
      asm volatile("s_waitcnt vmcnt(0)" ::: "memory");
      __builtin_amdgcn_sched_barrier(0);
    } while (!__all(v >= ep));
  }
  __syncthreads();
}

// ---------------- persistent recurrent kernel (one chunk of 128 steps) ----------------
// 256 WGs x 128 thr; WG = (g=bid&7 batch-group of 32 rows, j=bid>>3 slice of 16 cols).
// LDS: gate weight slices hi+lo = 128 KB; m-strip weights hi+lo in registers.
__global__ __launch_bounds__(128, 1) void k_rec(
    const uint16_t* __restrict__ wrh, const uint16_t* __restrict__ wrl,
    const float* __restrict__ blob,
    const float* __restrict__ b_ih, const float* __restrict__ b_hh,
    const float* __restrict__ mx_b, const float* __restrict__ mh_b,
    const float* __restrict__ h0, const float* __restrict__ c0,
    const int* __restrict__ lengths,
    uint16_t* hh, uint16_t* hl, uint16_t* mhp, uint16_t* mlp,
    float* cbuf, uint32_t* flags, float* out, int chunk) {
  extern __shared__ char smraw[];
  s8v* SW = (s8v*)smraw;  // [plane 2][gate 4][kt 16][lane 64] 16B frags
  int tid = threadIdx.x, l = tid & 63, mt = tid >> 6;
  int g = blockIdx.x & 7, j = blockIdx.x >> 3;

  for (int p = 0; p < 2; ++p) {
    const uint16_t* wp = p ? wrl : wrh;
    for (int nt = 0; nt < 4; ++nt) {
      const s8v* src = (const s8v*)(wp + (size_t)(nt * 32 + j) * 8192);
#pragma unroll
      for (int it = 0; it < 8; ++it) SW[p * 4096 + nt * 1024 + it * 128 + tid] = src[it * 128 + tid];
    }
  }
  s8v wmh[16], wml[16];  // m-strip (mh_w) frags, register-resident
  {
    const s8v* sH = (const s8v*)(wrh + (size_t)(128 + j) * 8192);
    const s8v* sL = (const s8v*)(wrl + (size_t)(128 + j) * 8192);
#pragma unroll
    for (int kt = 0; kt < 16; ++kt) { wmh[kt] = sH[kt * 64 + l]; wml[kt] = sL[kt * 64 + l]; }
  }
  int cidx = l & 15, rq = l >> 4;
  int hc = j * 16 + cidx;
  float mhb = mh_b[hc], mxb = mx_b[hc];
  float bsum[4];
#pragma unroll
  for (int nt = 0; nt < 4; ++nt) bsum[nt] = b_ih[nt * 512 + hc] + b_hh[nt * 512 + hc];
  int rowA = g * 32 + mt * 16 + cidx;        // A-frag row (global batch row)
  int kofs = rq * 8;
  int rowC0 = g * 32 + mt * 16 + rq * 4;     // C-frag row base
  float creg[4];
  int lenr[4];
#pragma unroll
  for (int ri = 0; ri < 4; ++ri) {
    int r = rowC0 + ri;
    lenr[ri] = lengths[r];
    creg[ri] = (chunk == 0) ? c0[hc] : cbuf[(size_t)r * 512 + hc];
  }
  if (chunk == 0) {
    uint16_t hi, lo;
    split2(h0[hc], hi, lo);
#pragma unroll
    for (int ri = 0; ri < 4; ++ri) {
      st16_sc1(hh + (size_t)(rowC0 + ri) * 512 + hc, hi);
      st16_sc1(hl + (size_t)(rowC0 + ri) * 512 + hc, lo);
    }
  }
  uint32_t* slots = flags + g * 64;
  uint32_t ep = 1;
  gbar(slots, j, ep);  // h planes ready (also covers LDS fill via its syncthreads)

  const uint16_t* hrb = hh + (size_t)rowA * 512 + kofs;
  const uint16_t* lrb = hl + (size_t)rowA * 512 + kofs;
  const uint16_t* mrb = mhp + (size_t)rowA * 512 + kofs;
  const uint16_t* nrb = mlp + (size_t)rowA * 512 + kofs;

  for (int t = 0; t < 128; ++t) {
    size_t bb = ((size_t)(t * 160 + j) * 8 + g) * 512 + (size_t)(mt * 16 + rq * 4) * 16 + cidx;
    // early blob loads (plain, L2-cacheable; compiler-managed waits)
    float bxm[4], bg[4][4];
#pragma unroll
    for (int ri = 0; ri < 4; ++ri) {
      bxm[ri] = blob[bb + 524288 + ri * 16];
#pragma unroll
      for (int nt = 0; nt < 4; ++nt) bg[nt][ri] = blob[bb + nt * 131072 + ri * 16];
    }
    // ---- P1: m = (xm + mx_b) * (h @ mh_w^T + mh_b) ----
    s8v ah[16], al[16];
#pragma unroll
    for (int kt = 0; kt < 16; ++kt) {
      ah[kt] = ldx4_sc1(hrb + kt * 32);
      al[kt] = ldx4_sc1(lrb + kt * 32);
    }
    asm volatile("s_waitcnt vmcnt(0)" ::: "memory");
    __builtin_amdgcn_sched_barrier(0);
    f4v a1a0 = (f4v){0,0,0,0}, a1a1 = (f4v){0,0,0,0}, a1c0 = (f4v){0,0,0,0}, a1c1 = (f4v){0,0,0,0};
#pragma unroll
    for (int kt = 0; kt < 16; kt += 2) {
      a1a0 = mf(ah[kt], wmh[kt], a1a0);
      a1a1 = mf(ah[kt + 1], wmh[kt + 1], a1a1);
    }
#pragma unroll
    for (int kt = 0; kt < 16; ++kt) {
      a1c0 = mf(ah[kt], wml[kt], a1c0);
      a1c1 = mf(al[kt], wmh[kt], a1c1);
    }
#pragma unroll
    for (int ri = 0; ri < 4; ++ri) {
      float hv = a1a0[ri] + a1a1[ri] + (a1c0[ri] + a1c1[ri]) * ISC + mhb;
      float mv = (bxm[ri] + mxb) * hv;
      uint16_t hi, lo;
      split2(mv, hi, lo);
      st16_sc1(mhp + (size_t)(rowC0 + ri) * 512 + hc, hi);
      st16_sc1(mlp + (size_t)(rowC0 + ri) * 512 + hc, lo);
    }
    ++ep;
    gbar(slots, j, ep);
    // ---- P2: gates = xg + m @ W_hh^T + b; update c,h ----
#pragma unroll
    for (int kt = 0; kt < 16; ++kt) {
      ah[kt] = ldx4_sc1(mrb + kt * 32);
      al[kt] = ldx4_sc1(nrb + kt * 32);
    }
    asm volatile("s_waitcnt vmcnt(0)" ::: "memory");
    __builtin_amdgcn_sched_barrier(0);
    f4v p2a[4], p2c[4];
#pragma unroll
    for (int nt = 0; nt < 4; ++nt) { p2a[nt] = (f4v){0,0,0,0}; p2c[nt] = (f4v){0,0,0,0}; }
#pragma unroll
    for (int kt = 0; kt < 16; ++kt)
#pragma unroll
      for (int nt = 0; nt < 4; ++nt) p2a[nt] = mf(ah[kt], SW[nt * 1024 + kt * 64 + l], p2a[nt]);
#pragma unroll
    for (int kt = 0; kt < 16; ++kt)
#pragma unroll
      for (int nt = 0; nt < 4; ++nt) {
        p2c[nt] = mf(ah[kt], SW[4096 + nt * 1024 + kt * 64 + l], p2c[nt]);
        p2c[nt] = mf(al[kt], SW[nt * 1024 + kt * 64 + l], p2c[nt]);
      }
#pragma unroll
    for (int ri = 0; ri < 4; ++ri) {
      float gi = p2a[0][ri] + p2c[0][ri] * ISC + bsum[0] + bg[0][ri];
      float gf = p2a[1][ri] + p2c[1][ri] * ISC + bsum[1] + bg[1][ri];
      float gc = p2a[2][ri] + p2c[2][ri] * ISC + bsum[2] + bg[2][ri];
      float go = p2a[3][ri] + p2c[3][ri] * ISC + bsum[3] + bg[3][ri];
      float iv = sigm(gi), fv = sigm(gf), gv = tanh_f(gc), ov = sigm(go);
      float cn = fv * creg[ri] + iv * gv;
      float hn = ov * tanh_f(cn);
      bool act = (chunk * 128 + t) < lenr[ri];
      if (act) {
        creg[ri] = cn;
        uint16_t hi, lo;
        split2(hn, hi, lo);
        st16_sc1(hh + (size_t)(rowC0 + ri) * 512 + hc, hi);
        st16_sc1(hl + (size_t)(rowC0 + ri) * 512 + hc, lo);
      }
    }
    ++ep;
    gbar(slots, j, ep);
  }
#pragma unroll
  for (int ri = 0; ri < 4; ++ri) {
    cbuf[(size_t)(rowC0 + ri) * 512 + hc] = creg[ri];
    if (chunk == 3) out[(size_t)(rowC0 + ri) * 512 + hc] = creg[ri];
  }
}

extern "C" void kernel_launch(void* const* d_in, const int* in_sizes, int n_in,
                              void* d_out, int out_size, void* d_ws, size_t ws_size,
                              hipStream_t stream) {
  (void)in_sizes; (void)n_in; (void)out_size;
  const float* x = (const float*)d_in[0];
  const int* lengths = (const int*)d_in[1];  // harness: integer inputs are int32
  const float* W_ih = (const float*)d_in[2];
  const float* W_hh = (const float*)d_in[3];
  const float* b_ih = (const float*)d_in[4];
  const float* b_hh = (const float*)d_in[5];
  const float* mx_w = (const float*)d_in[6];
  const float* mx_b = (const float*)d_in[7];
  const float* mh_w = (const float*)d_in[8];
  const float* mh_b = (const float*)d_in[9];
  const float* h0 = (const float*)d_in[10];
  const float* c0 = (const float*)d_in[11];

  if (ws_size < 616040448ull) return;  // clean failure signal

  char* ws = (char*)d_ws;
  uint16_t* xh = (uint16_t*)(ws);
  uint16_t* xl = (uint16_t*)(ws + 134217728ull);
  uint16_t* wpre_h = (uint16_t*)(ws + 268435456ull);
  uint16_t* wpre_l = (uint16_t*)(ws + 271056896ull);
  uint16_t* wrec_h = (uint16_t*)(ws + 273678336ull);
  uint16_t* wrec_l = (uint16_t*)(ws + 276299776ull);
  float* blob = (float*)(ws + 278921216ull);
  uint16_t* hh = (uint16_t*)(ws + 614465536ull);
  uint16_t* hl = (uint16_t*)(ws + 614727680ull);
  uint16_t* mhp = (uint16_t*)(ws + 614989824ull);
  uint16_t* mlp = (uint16_t*)(ws + 615251968ull);
  float* cbuf = (float*)(ws + 615514112ull);
  uint32_t* flags = (uint32_t*)(ws + 616038400ull);

  k_split<<<32768, 256, 0, stream>>>(x, xh, xl, 67108864L);
  k_packw<<<2560, 64, 0, stream>>>(W_ih, mx_w, wpre_h, wpre_l);
  k_packw<<<2560, 64, 0, stream>>>(W_hh, mh_w, wrec_h, wrec_l);
  hipFuncSetAttribute(reinterpret_cast<const void*>(k_rec),
                      hipFuncAttributeMaxDynamicSharedMemorySize, 131072);
  for (int c = 0; c < 4; ++c) {
    k_gemm3<<<dim3(20, 256), 256, 0, stream>>>(xh, xl, wpre_h, wpre_l, blob, c * 32768);
    hipMemsetAsync(flags, 0, 2048, stream);
    k_rec<<<256, 128, 131072, stream>>>(wrec_h, wrec_l, blob, b_ih, b_hh, mx_b, mh_b,
                                        h0, c0, lengths, hh, hl, mhp, mlp, cbuf,
                                        flags, (float*)d_out, c);
  }
}

// Round 7
// 8448.026 us; speedup vs baseline: 1.0378x; 1.0378x over previous
//
#include <hip/hip_runtime.h>
#include <stdint.h>

// mLSTM T=512,B=256,I=H=512 — fp32-equivalent via fp16 hi/lo MFMA (3-pass).
// Round 7: spill-free, wave-autonomous recurrence.
//  - 16 sub-groups of 16 batch rows; each 64-lane wave is an independent
//    barrier participant (no __syncthreads in the main loop).
//  - m-strip lo weights in LDS (9 slices, 144 KB); A-frags loaded in hi/lo
//    halves reusing one af[16] array -> peak ~200 VGPR, no scratch spills.
//  - slot barrier per wave: sc1 epoch store + hot check-then-sleep poll.
// ws layout (bytes):
//   xh     @ 0          x hi fp16                 134,217,728
//   xl     @ 134217728  x lo fp16 (scaled 2^11)   134,217,728
//   wpre_h @ 268435456  [W_ih;mx_w] frags hi        2,621,440
//   wpre_l @ 271056896  lo                          2,621,440
//   wrec_h @ 273678336  [W_hh;mh_w] frags hi        2,621,440
//   wrec_l @ 276299776  lo                          2,621,440
//   blob   @ 278921216  xg/xm fp32, 1 chunk (128 steps) 335,544,320
//   hh     @ 614465536  h hi plane u16[256][512]     262,144
//   hl     @ 614727680  h lo plane                   262,144
//   mhp    @ 614989824  m hi plane                   262,144
//   mlp    @ 615251968  m lo plane                   262,144
//   cbuf   @ 615514112  c state fp32                 524,288
//   flags  @ 616038400  mslots[16][32] + hslots[16][32]  4,096
// total 616,042,496

typedef __attribute__((ext_vector_type(8))) short s8v;
typedef __attribute__((ext_vector_type(8))) _Float16 h8v;
typedef __attribute__((ext_vector_type(4))) float f4v;

#define SC 2048.0f
#define ISC (1.0f / 2048.0f)

__device__ __forceinline__ f4v mf(s8v a, s8v b, f4v c) {
  return __builtin_amdgcn_mfma_f32_16x16x32_f16(
      __builtin_bit_cast(h8v, a), __builtin_bit_cast(h8v, b), c, 0, 0, 0);
}
__device__ __forceinline__ uint16_t f2h(float x) {
  _Float16 h = (_Float16)x;
  return __builtin_bit_cast(uint16_t, h);
}
__device__ __forceinline__ void split2(float v, uint16_t& hi, uint16_t& lo) {
  _Float16 h = (_Float16)v;
  float r = v - (float)h;
  hi = __builtin_bit_cast(uint16_t, h);
  lo = f2h(r * SC);
}
__device__ __forceinline__ float sigm(float x) { return 1.0f / (1.0f + __expf(-x)); }
__device__ __forceinline__ float tanh_f(float x) { return 1.0f - 2.0f / (__expf(2.0f * x) + 1.0f); }

// ---- sc1 (device-coherent) accessors for cross-wave state ----
__device__ __forceinline__ s8v ldx4_sc1(const uint16_t* p) {
  s8v r;
  asm volatile("global_load_dwordx4 %0, %1, off sc1" : "=v"(r) : "v"(p));
  return r;
}
__device__ __forceinline__ uint32_t ld32_sc1(const uint32_t* p) {
  uint32_t r;
  asm volatile("global_load_dword %0, %1, off sc1" : "=v"(r) : "v"(p));
  return r;
}
__device__ __forceinline__ void st16_sc1(uint16_t* p, uint32_t v) {
  asm volatile("global_store_short %0, %1, off sc1" ::"v"(p), "v"(v) : "memory");
}
__device__ __forceinline__ void st32_sc1(uint32_t* p, uint32_t v) {
  asm volatile("global_store_dword %0, %1, off sc1" ::"v"(p), "v"(v) : "memory");
}
#define VM0                                              \
  do {                                                   \
    asm volatile("s_waitcnt vmcnt(0)" ::: "memory");     \
    __builtin_amdgcn_sched_barrier(0);                   \
  } while (0)

// ---------------- split x fp32 -> fp16 hi/lo planes ----------------
__global__ __launch_bounds__(256) void k_split(const float* __restrict__ x,
                                               uint16_t* __restrict__ xh,
                                               uint16_t* __restrict__ xl, long n) {
  long i = ((long)blockIdx.x * 256 + threadIdx.x) * 8;
  if (i >= n) return;
  float4 a = *(const float4*)(x + i);
  float4 b = *(const float4*)(x + i + 4);
  union { uint16_t u[8]; s8v v; } oh, ol;
  float vv[8] = {a.x, a.y, a.z, a.w, b.x, b.y, b.z, b.w};
#pragma unroll
  for (int k = 0; k < 8; ++k) split2(vv[k], oh.u[k], ol.u[k]);
  *(s8v*)(xh + i) = oh.v;
  *(s8v*)(xl + i) = ol.v;
}

// ---------------- pack weights into MFMA B-fragment order, hi/lo ----------------
__global__ __launch_bounds__(64) void k_packw(const float* __restrict__ Wg,
                                              const float* __restrict__ Wm,
                                              uint16_t* __restrict__ wh,
                                              uint16_t* __restrict__ wl) {
  int s = blockIdx.x >> 4, kt = blockIdx.x & 15, l = threadIdx.x;
  const float* src = (s < 128) ? (Wg + (size_t)(s * 16 + (l & 15)) * 512)
                               : (Wm + (size_t)((s - 128) * 16 + (l & 15)) * 512);
  int k0 = kt * 32 + (l >> 4) * 8;
  float4 a = *(const float4*)(src + k0);
  float4 b = *(const float4*)(src + k0 + 4);
  union { uint16_t u[8]; s8v v; } oh, ol;
  float vv[8] = {a.x, a.y, a.z, a.w, b.x, b.y, b.z, b.w};
#pragma unroll
  for (int k = 0; k < 8; ++k) split2(vv[k], oh.u[k], ol.u[k]);
  size_t adr = ((size_t)(s * 16 + kt) * 64 + l) * 8;
  *(s8v*)(wh + adr) = oh.v;
  *(s8v*)(wl + adr) = ol.v;
}

// ---------------- one K-pass of the precompute GEMM ----------------
__device__ __forceinline__ void gpass(const uint16_t* __restrict__ Ap,
                                      const uint16_t* __restrict__ Bp,
                                      s8v* Asm, s8v* Bsm, int rowbase, int s0,
                                      f4v (&acc)[4][4]) {
  int tid = threadIdx.x;
  int wv = tid >> 6, l = tid & 63, wm = wv >> 1, wn = wv & 1;
  int arow = tid >> 1, ahalf = tid & 1, swz = (arow & 7) << 4;
  for (int ks = 0; ks < 8; ++ks) {
    __syncthreads();
    const uint16_t* asrc = Ap + (size_t)(rowbase + arow) * 512 + ks * 64;
#pragma unroll
    for (int q = 0; q < 4; ++q) {
      int pb = ahalf * 64 + q * 16;
      Asm[arow * 8 + (pb >> 4)] = *(const s8v*)(asrc + ((pb ^ swz) >> 1));
    }
#pragma unroll
    for (int q = 0; q < 4; ++q) {
      int ofs = tid * 64 + q * 16;
      int si = ofs >> 11, kti = (ofs >> 10) & 1, inner = ofs & 1023;
      Bsm[ofs >> 4] =
          *(const s8v*)(Bp + (size_t)((s0 + si) * 16 + ks * 2 + kti) * 512 + (inner >> 1));
    }
    __syncthreads();
#pragma unroll
    for (int kti = 0; kti < 2; ++kti) {
      s8v a[4], b[4];
#pragma unroll
      for (int i = 0; i < 4; ++i) {
        int row = wm * 64 + i * 16 + (l & 15);
        int lb = kti * 64 + (l >> 4) * 16;
        a[i] = Asm[row * 8 + ((lb ^ ((l & 7) << 4)) >> 4)];
      }
#pragma unroll
      for (int jj = 0; jj < 4; ++jj) b[jj] = Bsm[((wn * 4 + jj) * 2 + kti) * 64 + l];
#pragma unroll
      for (int i = 0; i < 4; ++i)
#pragma unroll
        for (int jj = 0; jj < 4; ++jj) acc[i][jj] = mf(a[i], b[jj], acc[i][jj]);
    }
  }
}

// ---------------- 3-pass precompute GEMM, fp32 blob out ----------------
// blob tile layout per chunk: ((t*160+s)*16+gg)*256 + rr*16 + cc  (16-row tiles)
__global__ __launch_bounds__(256, 2) void k_gemm3(const uint16_t* __restrict__ xh,
                                                  const uint16_t* __restrict__ xl,
                                                  const uint16_t* __restrict__ wh,
                                                  const uint16_t* __restrict__ wl,
                                                  float* __restrict__ blob, int row0) {
  __shared__ s8v Asm[1024], Bsm[1024];
  f4v acc_a[4][4], acc_c[4][4];
#pragma unroll
  for (int i = 0; i < 4; ++i)
#pragma unroll
    for (int jj = 0; jj < 4; ++jj) {
      acc_a[i][jj] = (f4v){0.f, 0.f, 0.f, 0.f};
      acc_c[i][jj] = (f4v){0.f, 0.f, 0.f, 0.f};
    }
  int s0 = blockIdx.x * 8, r0 = blockIdx.y * 128;
  int rowbase = row0 + r0;
  gpass(xh, wh, Asm, Bsm, rowbase, s0, acc_a);
  gpass(xh, wl, Asm, Bsm, rowbase, s0, acc_c);
  gpass(xl, wh, Asm, Bsm, rowbase, s0, acc_c);
  int tid = threadIdx.x, wv = tid >> 6, l = tid & 63, wm = wv >> 1, wn = wv & 1;
#pragma unroll
  for (int i = 0; i < 4; ++i)
#pragma unroll
    for (int jj = 0; jj < 4; ++jj) {
      int s = s0 + wn * 4 + jj;
#pragma unroll
      for (int ri = 0; ri < 4; ++ri) {
        int trow = r0 + wm * 64 + i * 16 + (l >> 4) * 4 + ri;  // chunk-local row
        int tt = trow >> 8, gg = (trow >> 4) & 15, rr = trow & 15;
        size_t adr = ((size_t)(tt * 160 + s) * 16 + gg) * 256 + rr * 16 + (l & 15);
        blob[adr] = acc_a[i][jj][ri] + acc_c[i][jj][ri] * ISC;
      }
    }
}

// ---------------- per-wave slot poll (32 slots, lanes duplicate x2) ----------------
__device__ __forceinline__ void spoll(const uint32_t* slots, uint32_t ep, int l) {
  const uint32_t* q = slots + (l & 31);
  for (;;) {
    uint32_t v = ld32_sc1(q);
    VM0;
    if (__all((int)(v >= ep))) break;
    __builtin_amdgcn_s_sleep(1);
  }
}

// ---------------- persistent recurrent kernel (one chunk of 128 steps) ----------------
// 256 WGs x 128 thr. WG w: j = w>>3 (16-col slice). Wave wv: gg = 2*(w&7)+wv
// (16-row batch sub-group). Waves are fully independent after LDS fill.
__global__ __launch_bounds__(128, 1) void k_rec(
    const uint16_t* __restrict__ wrh, const uint16_t* __restrict__ wrl,
    const float* __restrict__ blob,
    const float* __restrict__ b_ih, const float* __restrict__ b_hh,
    const float* __restrict__ mx_b, const float* __restrict__ mh_b,
    const float* __restrict__ h0, const float* __restrict__ c0,
    const int* __restrict__ lengths,
    uint16_t* hh, uint16_t* hl, uint16_t* mhp, uint16_t* mlp,
    float* cbuf, uint32_t* flags, float* out, int chunk) {
  extern __shared__ char smraw[];
  s8v* SW = (s8v*)smraw;  // slices: 0-3 gate hi, 4-7 gate lo, 8 m-strip lo (144 KB)
  int tid = threadIdx.x, l = tid & 63, wv = tid >> 6;
  int j = blockIdx.x >> 3, gg = ((blockIdx.x & 7) << 1) | wv;

#pragma unroll
  for (int sl = 0; sl < 9; ++sl) {
    int gs = (sl < 4) ? (sl * 32 + j) : (sl < 8 ? (sl - 4) * 32 + j : 128 + j);
    const s8v* src = (const s8v*)(((sl < 4) ? wrh : wrl) + (size_t)gs * 8192);
#pragma unroll
    for (int it = 0; it < 8; ++it) SW[sl * 1024 + it * 128 + tid] = src[it * 128 + tid];
  }
  s8v wmh[16];  // m-strip hi weights, register-resident (loop-invariant)
  {
    const s8v* sH = (const s8v*)(wrh + (size_t)(128 + j) * 8192);
#pragma unroll
    for (int kt = 0; kt < 16; ++kt) wmh[kt] = sH[kt * 64 + l];
  }
  __syncthreads();  // LDS ready; waves independent from here on

  int cidx = l & 15, rq = l >> 4;
  int hc = j * 16 + cidx;
  float mhb = mh_b[hc], mxb = mx_b[hc];
  float bsum[4];
#pragma unroll
  for (int nt = 0; nt < 4; ++nt) bsum[nt] = b_ih[nt * 512 + hc] + b_hh[nt * 512 + hc];
  int rowA = gg * 16 + cidx;       // A-frag row (global batch row)
  int kofs = rq * 8;
  int rowC0 = gg * 16 + rq * 4;    // C-frag row base
  float creg[4];
  int lenr[4];
#pragma unroll
  for (int ri = 0; ri < 4; ++ri) {
    int r = rowC0 + ri;
    lenr[ri] = lengths[r];
    creg[ri] = (chunk == 0) ? c0[hc] : cbuf[(size_t)r * 512 + hc];
  }
  uint32_t* mslot = flags + gg * 32;
  uint32_t* hslot = flags + 512 + gg * 32;

  if (chunk == 0) {
    uint16_t hi, lo;
    split2(h0[hc], hi, lo);
#pragma unroll
    for (int ri = 0; ri < 4; ++ri) {
      st16_sc1(hh + (size_t)(rowC0 + ri) * 512 + hc, hi);
      st16_sc1(hl + (size_t)(rowC0 + ri) * 512 + hc, lo);
    }
  }
  asm volatile("s_waitcnt vmcnt(0)" ::: "memory");
  if (l == 0) st32_sc1(hslot + j, 1u);
  spoll(hslot, 1u, l);

  const uint16_t* hrb = hh + (size_t)rowA * 512 + kofs;
  const uint16_t* lrb = hl + (size_t)rowA * 512 + kofs;
  const uint16_t* mrb = mhp + (size_t)rowA * 512 + kofs;
  const uint16_t* nrb = mlp + (size_t)rowA * 512 + kofs;

  for (int t = 0; t < 128; ++t) {
    // blob loads for this step (issued before polls; drained by first poll's wait)
    size_t tb = ((size_t)(t * 160) * 16 + (size_t)gg) * 256 + rq * 64 + cidx;
    float bxm[4], bg[4][4];
#pragma unroll
    for (int ri = 0; ri < 4; ++ri) {
      bxm[ri] = blob[tb + (size_t)(128 + j) * 4096 + ri * 16];
#pragma unroll
      for (int nt = 0; nt < 4; ++nt)
        bg[nt][ri] = blob[tb + (size_t)(nt * 32 + j) * 4096 + ri * 16];
    }
    if (t > 0) spoll(hslot, (uint32_t)(t + 1), l);  // t==0 already satisfied
    // ---- P1: m = (xm + mx_b) * (h @ mh_w^T + mh_b) ----
    s8v af[16];
#pragma unroll
    for (int kt = 0; kt < 16; ++kt) af[kt] = ldx4_sc1(hrb + kt * 32);
    VM0;
    f4v a1a0 = (f4v){0,0,0,0}, a1a1 = (f4v){0,0,0,0};
    f4v a1c0 = (f4v){0,0,0,0}, a1c1 = (f4v){0,0,0,0};
#pragma unroll
    for (int kt = 0; kt < 16; kt += 2) {
      a1a0 = mf(af[kt], wmh[kt], a1a0);
      a1a1 = mf(af[kt + 1], wmh[kt + 1], a1a1);
    }
#pragma unroll
    for (int kt = 0; kt < 16; ++kt) a1c0 = mf(af[kt], SW[8 * 1024 + kt * 64 + l], a1c0);
#pragma unroll
    for (int kt = 0; kt < 16; ++kt) af[kt] = ldx4_sc1(lrb + kt * 32);
    VM0;
#pragma unroll
    for (int kt = 0; kt < 16; ++kt) a1c1 = mf(af[kt], wmh[kt], a1c1);
#pragma unroll
    for (int ri = 0; ri < 4; ++ri) {
      float hv = a1a0[ri] + a1a1[ri] + (a1c0[ri] + a1c1[ri]) * ISC + mhb;
      float mv = (bxm[ri] + mxb) * hv;
      uint16_t hi, lo;
      split2(mv, hi, lo);
      st16_sc1(mhp + (size_t)(rowC0 + ri) * 512 + hc, hi);
      st16_sc1(mlp + (size_t)(rowC0 + ri) * 512 + hc, lo);
    }
    asm volatile("s_waitcnt vmcnt(0)" ::: "memory");
    if (l == 0) st32_sc1(mslot + j, (uint32_t)(t + 1));
    spoll(mslot, (uint32_t)(t + 1), l);
    // ---- P2: gates = xg + m @ W_hh^T + b; update c,h ----
    f4v p2a[4], p2c[4], p2d[4];
#pragma unroll
    for (int nt = 0; nt < 4; ++nt) {
      p2a[nt] = (f4v){0,0,0,0};
      p2c[nt] = (f4v){0,0,0,0};
      p2d[nt] = (f4v){0,0,0,0};
    }
#pragma unroll
    for (int kt = 0; kt < 16; ++kt) af[kt] = ldx4_sc1(mrb + kt * 32);
    VM0;
#pragma unroll
    for (int kt = 0; kt < 16; ++kt)
#pragma unroll
      for (int nt = 0; nt < 4; ++nt) {
        p2a[nt] = mf(af[kt], SW[nt * 1024 + kt * 64 + l], p2a[nt]);
        p2c[nt] = mf(af[kt], SW[(4 + nt) * 1024 + kt * 64 + l], p2c[nt]);
      }
#pragma unroll
    for (int kt = 0; kt < 16; ++kt) af[kt] = ldx4_sc1(nrb + kt * 32);
    VM0;
#pragma unroll
    for (int kt = 0; kt < 16; ++kt)
#pragma unroll
      for (int nt = 0; nt < 4; ++nt) p2d[nt] = mf(af[kt], SW[nt * 1024 + kt * 64 + l], p2d[nt]);
#pragma unroll
    for (int ri = 0; ri < 4; ++ri) {
      float gi = p2a[0][ri] + (p2c[0][ri] + p2d[0][ri]) * ISC + bsum[0] + bg[0][ri];
      float gf = p2a[1][ri] + (p2c[1][ri] + p2d[1][ri]) * ISC + bsum[1] + bg[1][ri];
      float gc = p2a[2][ri] + (p2c[2][ri] + p2d[2][ri]) * ISC + bsum[2] + bg[2][ri];
      float go = p2a[3][ri] + (p2c[3][ri] + p2d[3][ri]) * ISC + bsum[3] + bg[3][ri];
      float iv = sigm(gi), fv = sigm(gf), gv = tanh_f(gc), ov = sigm(go);
      float cn = fv * creg[ri] + iv * gv;
      float hn = ov * tanh_f(cn);
      bool act = (chunk * 128 + t) < lenr[ri];
      if (act) {
        creg[ri] = cn;
        uint16_t hi, lo;
        split2(hn, hi, lo);
        st16_sc1(hh + (size_t)(rowC0 + ri) * 512 + hc, hi);
        st16_sc1(hl + (size_t)(rowC0 + ri) * 512 + hc, lo);
      }
    }
    if (t < 127) {
      asm volatile("s_waitcnt vmcnt(0)" ::: "memory");
      if (l == 0) st32_sc1(hslot + j, (uint32_t)(t + 2));
    }
  }
#pragma unroll
  for (int ri = 0; ri < 4; ++ri) {
    cbuf[(size_t)(rowC0 + ri) * 512 + hc] = creg[ri];
    if (chunk == 3) out[(size_t)(rowC0 + ri) * 512 + hc] = creg[ri];
  }
}

extern "C" void kernel_launch(void* const* d_in, const int* in_sizes, int n_in,
                              void* d_out, int out_size, void* d_ws, size_t ws_size,
                              hipStream_t stream) {
  (void)in_sizes; (void)n_in; (void)out_size;
  const float* x = (const float*)d_in[0];
  const int* lengths = (const int*)d_in[1];  // harness: integer inputs are int32
  const float* W_ih = (const float*)d_in[2];
  const float* W_hh = (const float*)d_in[3];
  const float* b_ih = (const float*)d_in[4];
  const float* b_hh = (const float*)d_in[5];
  const float* mx_w = (const float*)d_in[6];
  const float* mx_b = (const float*)d_in[7];
  const float* mh_w = (const float*)d_in[8];
  const float* mh_b = (const float*)d_in[9];
  const float* h0 = (const float*)d_in[10];
  const float* c0 = (const float*)d_in[11];

  if (ws_size < 616042496ull) return;  // clean failure signal

  char* ws = (char*)d_ws;
  uint16_t* xh = (uint16_t*)(ws);
  uint16_t* xl = (uint16_t*)(ws + 134217728ull);
  uint16_t* wpre_h = (uint16_t*)(ws + 268435456ull);
  uint16_t* wpre_l = (uint16_t*)(ws + 271056896ull);
  uint16_t* wrec_h = (uint16_t*)(ws + 273678336ull);
  uint16_t* wrec_l = (uint16_t*)(ws + 276299776ull);
  float* blob = (float*)(ws + 278921216ull);
  uint16_t* hh = (uint16_t*)(ws + 614465536ull);
  uint16_t* hl = (uint16_t*)(ws + 614727680ull);
  uint16_t* mhp = (uint16_t*)(ws + 614989824ull);
  uint16_t* mlp = (uint16_t*)(ws + 615251968ull);
  float* cbuf = (float*)(ws + 615514112ull);
  uint32_t* flags = (uint32_t*)(ws + 616038400ull);

  k_split<<<32768, 256, 0, stream>>>(x, xh, xl, 67108864L);
  k_packw<<<2560, 64, 0, stream>>>(W_ih, mx_w, wpre_h, wpre_l);
  k_packw<<<2560, 64, 0, stream>>>(W_hh, mh_w, wrec_h, wrec_l);
  hipFuncSetAttribute(reinterpret_cast<const void*>(k_rec),
                      hipFuncAttributeMaxDynamicSharedMemorySize, 147456);
  for (int c = 0; c < 4; ++c) {
    k_gemm3<<<dim3(20, 256), 256, 0, stream>>>(xh, xl, wpre_h, wpre_l, blob, c * 32768);
    hipMemsetAsync(flags, 0, 4096, stream);
    k_rec<<<256, 128, 147456, stream>>>(wrec_h, wrec_l, blob, b_ih, b_hh, mx_b, mh_b,
                                        h0, c0, lengths, hh, hl, mhp, mlp, cbuf,
                                        flags, (float*)d_out, c);
  }
}